// Round 14
// baseline (293.757 us; speedup 1.0000x reference)
//
#include <hip/hip_runtime.h>
#include <math.h>

#define Cc 512
#define Pp 1024
#define NROW 25088      // B*N = 8*3136
#define BM 128          // rows per block
#define BNP 128         // centroid cols per block (8 pblocks)
#define NMB 196         // real mblocks = 25088/128
#define NMB_PAD 200     // padded so mblocks group 8-per-XCD
#define BIAS 4096.f     // makes v = cn+BIAS-2dot strictly positive for packing

typedef short  bf16x8 __attribute__((ext_vector_type(8)));   // 8 bf16 = 4 VGPR
typedef float  f32x4  __attribute__((ext_vector_type(4)));
typedef unsigned short u16x8 __attribute__((ext_vector_type(8)));
typedef unsigned short u16x4 __attribute__((ext_vector_type(4)));

__device__ __forceinline__ unsigned short bf16_rne(float f) {
    unsigned int u = __float_as_uint(f);
    return (unsigned short)((u + 0x7fffu + ((u >> 16) & 1u)) >> 16);
}

// branch-free sorted insert (float), for cross-pblock merges
#define TOP3_INSERT(t0, t1, t2, v)                                  \
    do {                                                            \
        float _n0 = fminf((t0), (v));                               \
        float _h0 = fmaxf((t0), (v));                               \
        float _n1 = fminf((t1), _h0);                               \
        float _h1 = fmaxf((t1), _h0);                               \
        float _n2 = fminf((t2), _h1);                               \
        (t0) = _n0; (t1) = _n1; (t2) = _n2;                         \
    } while (0)

// branch-free sorted insert (packed u32: high-24 float bits | 8-bit col id)
#define TOP3_INS_U32(t0, t1, t2, v)                                 \
    do {                                                            \
        unsigned int _n0 = min((t0), (v));                          \
        unsigned int _h0 = max((t0), (v));                          \
        unsigned int _n1 = min((t1), _h0);                          \
        unsigned int _h1 = max((t1), _h0);                          \
        unsigned int _n2 = min((t2), _h1);                          \
        (t0) = _n0; (t1) = _n1; (t2) = _n2;                         \
    } while (0)

#define GLOAD_LDS16(gp, lp)                                             \
    __builtin_amdgcn_global_load_lds(                                   \
        (const __attribute__((address_space(1))) void*)(const void*)(gp),\
        (__attribute__((address_space(3))) void*)(void*)(lp), 16, 0, 0)

// ---------------------------------------------------------------------------
// Transpose-conv (proven): fp32 -> bf16 RNE, re-tiled into MFMA fragment
// order, fused row squared-norm.
// Tile = 16 rows x 32 k = 64 chunks of 16B; chunk (g,q) at lane l = g*16+q.
// Tile id = rowblk_base + kt*ktstride + nrt, rowblk_base = rb + (rb>>lg)*(15<<lg)
//   A (embeds):    lg=3, ktstride=8   -> [mblock][kstep 16][nrtile 8][64*16B]
//   B (centroids): lg=6, ktstride=64  -> [kstep 16][ptile 64][64*16B]
// ---------------------------------------------------------------------------
__global__ __launch_bounds__(256) void tconv_kernel(
        const float* __restrict__ src, unsigned short* __restrict__ dst,
        float* __restrict__ nrm, int lg, int ktstride) {
    __shared__ unsigned short buf[32 * 512];   // 32 KB
    __shared__ float snorm[32 * 8];            // 1 KB

    const int t = threadIdx.x;
    const size_t R0 = (size_t)blockIdx.x * 32;

    #pragma unroll
    for (int p = 0; p < 16; ++p) {
        int idx = p * 1024 + t * 4;
        float4 v = *(const float4*)(src + R0 * Cc + idx);
        u16x4 o;
        o[0] = bf16_rne(v.x); o[1] = bf16_rne(v.y);
        o[2] = bf16_rne(v.z); o[3] = bf16_rne(v.w);
        *(u16x4*)&buf[idx] = o;
    }
    __syncthreads();

    const int w = t >> 6, g = (t >> 4) & 3, q = t & 15, l = t & 63;
    const int rb = (int)(R0 >> 4);
    const int rowblk_base = rb + (rb >> lg) * (15 << lg);
    float fns = 0.f;
    #pragma unroll
    for (int p = 0; p < 8; ++p) {
        int cg  = p * 4 + w;              // tile-local group 0..31
        int kt  = cg >> 1, nrt = cg & 1;
        int row = nrt * 16 + q;
        u16x8 ch = *(const u16x8*)&buf[row * 512 + kt * 32 + g * 8];
        #pragma unroll
        for (int i = 0; i < 8; ++i) {
            float x = __uint_as_float((unsigned int)(unsigned short)ch[i] << 16);
            fns = fmaf(x, x, fns);
        }
        size_t tile = (size_t)rowblk_base + (size_t)kt * ktstride + nrt;
        *(u16x8*)(dst + tile * 512 + l * 8) = ch;
    }
    snorm[((w & 1) * 16 + q) * 8 + (w >> 1) * 4 + g] = fns;
    __syncthreads();
    if (t < 32) {
        float s = 0.f;
        #pragma unroll
        for (int j = 0; j < 8; ++j) s += snorm[t * 8 + j];
        nrm[R0 + t] = s;
    }
}

// ---------------------------------------------------------------------------
// Main (R12 structure + occupancy push): split-pipe 128x128 MFMA tile, TWO
// k-steps per barrier (32 MFMA/wave between barriers). A fragments direct
// global->VGPR prefetched 2 k-steps ahead; B double-buffered 2x16KB via
// gload_lds; counted vmcnt(8) per step (never 0 until tail). LDS trimmed to
// 32 KB (tops aliased into Blds post-loop) + __launch_bounds__(256,5) ->
// up to 5 blocks/CU co-resident (TLP covers per-wave L2-latency stalls).
// Fragment-ordered reads: contiguous 1KB/wave => conflict-free, no swizzle.
// Swapped-operand MFMA (cents lane-local in C) + packed-u32 top-3.
// Grid: 1600 blocks (200 padded mblocks x 8 pblocks), 256 thr = 4 waves 2x2.
// acc[mc][nr]: cent = p0+wn*64+mc*16+g*4+reg ; row = row0+wm*64+nr*16+q
// ---------------------------------------------------------------------------
__global__ __launch_bounds__(256, 5) void mfma_topk_kernel(
        const unsigned short* __restrict__ EbT, const unsigned short* __restrict__ CbT,
        const float* __restrict__ cnorm, float* __restrict__ wsTop) {
    const int xcd = blockIdx.x & 7;
    const int t8  = blockIdx.x >> 3;          // 0..199
    const int mblock = ((t8 >> 3) << 3) | xcd;
    const int pblock = t8 & 7;
    if (mblock >= NMB) return;                // uniform early-exit

    __shared__ unsigned short Blds[2][8192];  // 2 x 16 KB (2 k-panels each) = 32 KB

    const int tid  = threadIdx.x;
    const int lane = tid & 63;
    const int w    = tid >> 6;
    const int wm   = w >> 1;       // 0..1 row half
    const int wn   = w & 1;        // 0..1 cent half
    const int g    = lane >> 4;    // 0..3
    const int q    = lane & 15;    // 0..15
    const int row0 = mblock * BM;
    const int p0   = pblock * BNP;

    f32x4 acc[4][4];               // [mc][nr]
    #pragma unroll
    for (int mc = 0; mc < 4; ++mc)
        #pragma unroll
        for (int nr = 0; nr < 4; ++nr) acc[mc][nr] = (f32x4){0.f, 0.f, 0.f, 0.f};

    // A fragment base (u16): tile=512 u16, tiles [mblock][kt 16][nrt 8]
    const unsigned short* Ab = EbT + ((size_t)mblock * 128 + wm * 4) * 512 + lane * 8;
    // B: tiles [kt 16][ptile 64]; this block's 8 tiles per kt are contiguous
    const unsigned short* Bg = CbT + (size_t)pblock * 8 * 512;

    // stage TWO k-panels (kt = 2i, 2i+1) into buffer buf: 4 DMA instrs/thread
    auto STAGE_B2 = [&](int buf, int i) {
        #pragma unroll
        for (int ks = 0; ks < 2; ++ks) {
            const unsigned short* src = Bg + (size_t)(2 * i + ks) * 32768;
            #pragma unroll
            for (int it = 0; it < 2; ++it) {
                int c = tid + it * 256;
                GLOAD_LDS16(src + c * 8, (char*)Blds[buf] + ks * 8192 + c * 16);
            }
        }
    };

    bf16x8 af[2][2][4];            // [buf][ks][nr] = 64 VGPR
    STAGE_B2(0, 0);                // B iter0 (kt 0,1): 4 DMA
    #pragma unroll
    for (int ks = 0; ks < 2; ++ks)
        #pragma unroll
        for (int nr = 0; nr < 4; ++nr)
            af[0][ks][nr] = *(const bf16x8*)(Ab + (size_t)ks * 4096 + nr * 512);
    // in flight: B0(4 oldest) + A0(8) -> drain B0, keep A0
    asm volatile("s_waitcnt vmcnt(8)" ::: "memory");
    __builtin_amdgcn_s_barrier();

    #pragma unroll
    for (int i = 0; i < 8; ++i) {
        const int cur = i & 1, nxt = cur ^ 1;
        if (i < 7) {
            STAGE_B2(nxt, i + 1);                      // 4 DMA
            #pragma unroll
            for (int ks = 0; ks < 2; ++ks)
                #pragma unroll
                for (int nr = 0; nr < 4; ++nr)
                    af[nxt][ks][nr] = *(const bf16x8*)(
                        Ab + (size_t)(2 * i + 2 + ks) * 4096 + nr * 512);
        }

        #pragma unroll
        for (int ks = 0; ks < 2; ++ks) {
            const char* Bsk = (const char*)Blds[cur] + ks * 8192;
            bf16x8 bc[4];
            #pragma unroll
            for (int mc = 0; mc < 4; ++mc)
                bc[mc] = *(const bf16x8*)(Bsk + (wn * 4 + mc) * 1024 + lane * 16);
            __builtin_amdgcn_s_setprio(1);
            #pragma unroll
            for (int mc = 0; mc < 4; ++mc)
                #pragma unroll
                for (int nr = 0; nr < 4; ++nr)
                    acc[mc][nr] = __builtin_amdgcn_mfma_f32_16x16x32_bf16(
                        bc[mc], af[cur][ks][nr], acc[mc][nr], 0, 0, 0);
            __builtin_amdgcn_s_setprio(0);
        }

        // drain next iter's B(4); keep next iter's A(8) in flight
        if (i < 7) asm volatile("s_waitcnt vmcnt(8)" ::: "memory");
        else       asm volatile("s_waitcnt vmcnt(0)" ::: "memory");
        __builtin_amdgcn_s_barrier();
    }

    // ---- epilogue: cents lane-local; top-3 per row over 64 cents/wave ----
    // Blds is dead now (last barrier passed, no more B reads) -> alias tops.
    float* tops = (float*)Blds;    // [2][BM][3] floats = 3 KB

    float cnb[4][4];
    #pragma unroll
    for (int mc = 0; mc < 4; ++mc)
        #pragma unroll
        for (int reg = 0; reg < 4; ++reg)
            cnb[mc][reg] = cnorm[p0 + wn * 64 + mc * 16 + g * 4 + reg] + BIAS;

    #pragma unroll
    for (int nr = 0; nr < 4; ++nr) {
        unsigned int u0 = 0xFFFFFFFFu, u1 = 0xFFFFFFFFu, u2 = 0xFFFFFFFFu;
        #pragma unroll
        for (int mc = 0; mc < 4; ++mc)
            #pragma unroll
            for (int reg = 0; reg < 4; ++reg) {
                float v = fmaf(-2.f, acc[mc][nr][reg], cnb[mc][reg]);  // > 0
                unsigned int cl = (unsigned int)(wn * 64 + mc * 16 + g * 4 + reg);
                unsigned int u = (__float_as_uint(v) & 0xFFFFFF00u) | cl;
                TOP3_INS_U32(u0, u1, u2, u);
            }
        #pragma unroll
        for (int mask = 16; mask <= 32; mask <<= 1) {
            unsigned int o0 = (unsigned int)__shfl_xor((int)u0, mask);
            unsigned int o1 = (unsigned int)__shfl_xor((int)u1, mask);
            unsigned int o2 = (unsigned int)__shfl_xor((int)u2, mask);
            TOP3_INS_U32(u0, u1, u2, o0);
            TOP3_INS_U32(u0, u1, u2, o1);
            TOP3_INS_U32(u0, u1, u2, o2);
        }
        if (g == 0) {
            int rl = wm * 64 + nr * 16 + q;
            float* d = tops + ((size_t)wn * BM + rl) * 3;
            d[0] = __uint_as_float(u0 & 0xFFFFFF00u) - BIAS;
            d[1] = __uint_as_float(u1 & 0xFFFFFF00u) - BIAS;
            d[2] = __uint_as_float(u2 & 0xFFFFFF00u) - BIAS;
        }
    }
    __syncthreads();

    if (tid < BM) {
        const float* p = tops + (size_t)tid * 3;
        float a0v = p[0], a1v = p[1], a2v = p[2];
        const float* p1 = tops + ((size_t)BM + tid) * 3;
        TOP3_INSERT(a0v, a1v, a2v, p1[0]);
        TOP3_INSERT(a0v, a1v, a2v, p1[1]);
        TOP3_INSERT(a0v, a1v, a2v, p1[2]);
        float* dst = wsTop + (size_t)(row0 + tid) * 24 + pblock * 3;
        dst[0] = a0v; dst[1] = a1v; dst[2] = a2v;
    }
}

// ---------------------------------------------------------------------------
// Final merge: fold 8 pblocks' top3, add row norm, sqrt + softmin, store.
// ---------------------------------------------------------------------------
__global__ __launch_bounds__(256) void merge_kernel(
        const float* __restrict__ wsTop, const float* __restrict__ fnorm,
        float* __restrict__ out) {
    int r = blockIdx.x * 256 + threadIdx.x;      // 25088 = 98*256 exact
    const float* p = wsTop + (size_t)r * 24;
    float t0 = p[0], t1 = p[1], t2 = p[2];
    #pragma unroll
    for (int pb = 1; pb < 8; ++pb) {
        TOP3_INSERT(t0, t1, t2, p[pb * 3 + 0]);
        TOP3_INSERT(t0, t1, t2, p[pb * 3 + 1]);
        TOP3_INSERT(t0, t1, t2, p[pb * 3 + 2]);
    }
    float fn = fnorm[r];
    float d0 = sqrtf(fmaxf(fn + t0, 0.f));
    float d1 = sqrtf(fmaxf(fn + t1, 0.f));
    float d2 = sqrtf(fmaxf(fn + t2, 0.f));
    float w0 = 1.f / (1.f + __expf(d0 - d1) + __expf(d0 - d2));
    out[r] = w0 * d0;
}

extern "C" void kernel_launch(void* const* d_in, const int* in_sizes, int n_in,
                              void* d_out, int out_size, void* d_ws, size_t ws_size,
                              hipStream_t stream) {
    (void)in_sizes; (void)n_in; (void)out_size; (void)ws_size;
    const float* embeds    = (const float*)d_in[0];   // [8,3136,512] fp32
    const float* centroids = (const float*)d_in[1];   // [1024,512]  fp32
    float* out = (float*)d_out;

    // ws layout (bytes):
    //   cnorm  @ 0         (4 KB)
    //   fnorm  @ 4096      (100,352 B)
    //   wsTop  @ 104448    (25088*8*3*4 = 2,408,448 B)  [row][pblock][3]
    //   EbT    @ 2512896   (25,690,112 B bf16, fragment-tiled)
    //   CbT    @ 28203008  (1,048,576 B bf16, fragment-tiled)  total ~27.9 MB
    char* ws = (char*)d_ws;
    float*          cnorm = (float*)(ws);
    float*          fnorm = (float*)(ws + 4096);
    float*          wsTop = (float*)(ws + 104448);
    unsigned short* EbT   = (unsigned short*)(ws + 2512896);
    unsigned short* CbT   = (unsigned short*)(ws + 28203008);

    tconv_kernel<<<NROW / 32, 256, 0, stream>>>(embeds,    EbT, fnorm, 3, 8);
    tconv_kernel<<<Pp / 32,   256, 0, stream>>>(centroids, CbT, cnorm, 6, 64);
    mfma_topk_kernel<<<NMB_PAD * 8, 256, 0, stream>>>(EbT, CbT, cnorm, wsTop);
    merge_kernel<<<NROW / 256, 256, 0, stream>>>(wsTop, fnorm, out);
}

// Round 15
// 51.202 us; speedup vs baseline: 5.7372x; 5.7372x over previous
//
#include <hip/hip_runtime.h>
#include <math.h>

#define Cc 512
#define Pp 1024
#define NROW 25088      // B*N = 8*3136
#define BM 128          // rows per block
#define BNP 128         // centroid cols per block (8 pblocks)
#define NMB 196         // real mblocks = 25088/128
#define NMB_PAD 200     // padded so mblocks group 8-per-XCD
#define BIAS 4096.f     // makes v = cn+BIAS-2dot strictly positive for packing

typedef short  bf16x8 __attribute__((ext_vector_type(8)));   // 8 bf16 = 4 VGPR
typedef float  f32x4  __attribute__((ext_vector_type(4)));
typedef unsigned short u16x8 __attribute__((ext_vector_type(8)));
typedef unsigned short u16x4 __attribute__((ext_vector_type(4)));

__device__ __forceinline__ unsigned short bf16_rne(float f) {
    unsigned int u = __float_as_uint(f);
    return (unsigned short)((u + 0x7fffu + ((u >> 16) & 1u)) >> 16);
}

// branch-free sorted insert (float), for cross-pblock merges
#define TOP3_INSERT(t0, t1, t2, v)                                  \
    do {                                                            \
        float _n0 = fminf((t0), (v));                               \
        float _h0 = fmaxf((t0), (v));                               \
        float _n1 = fminf((t1), _h0);                               \
        float _h1 = fmaxf((t1), _h0);                               \
        float _n2 = fminf((t2), _h1);                               \
        (t0) = _n0; (t1) = _n1; (t2) = _n2;                         \
    } while (0)

// branch-free sorted insert (packed u32: high-24 float bits | 8-bit col id)
#define TOP3_INS_U32(t0, t1, t2, v)                                 \
    do {                                                            \
        unsigned int _n0 = min((t0), (v));                          \
        unsigned int _h0 = max((t0), (v));                          \
        unsigned int _n1 = min((t1), _h0);                          \
        unsigned int _h1 = max((t1), _h0);                          \
        unsigned int _n2 = min((t2), _h1);                          \
        (t0) = _n0; (t1) = _n1; (t2) = _n2;                         \
    } while (0)

#define GLOAD_LDS16(gp, lp)                                             \
    __builtin_amdgcn_global_load_lds(                                   \
        (const __attribute__((address_space(1))) void*)(const void*)(gp),\
        (__attribute__((address_space(3))) void*)(void*)(lp), 16, 0, 0)

// ---------------------------------------------------------------------------
// Fused transpose-conv (proven body): fp32 -> bf16 RNE, re-tiled into MFMA
// fragment order, fused row squared-norm. One launch covers BOTH inputs:
// blocks 0..783 process embeds (lg=3, kts=8), 784..815 centroids (lg=6,
// kts=64). Tile = 16 rows x 32 k = 64 chunks of 16B; chunk (g,q) at lane
// l = g*16+q. Tile id = rowblk_base + kt*kts + nrt,
// rowblk_base = rb + (rb>>lg)*(15<<lg).
// ---------------------------------------------------------------------------
__global__ __launch_bounds__(256) void tconv_fused_kernel(
        const float* __restrict__ embeds, const float* __restrict__ cents,
        unsigned short* __restrict__ EbT, unsigned short* __restrict__ CbT,
        float* __restrict__ fnorm, float* __restrict__ cnorm) {
    __shared__ unsigned short buf[32 * 512];   // 32 KB
    __shared__ float snorm[32 * 8];            // 1 KB

    const int bid = blockIdx.x;
    const bool isE = bid < (NROW / 32);
    const float*    src = isE ? embeds : cents;
    unsigned short* dst = isE ? EbT : CbT;
    float*          nrm = isE ? fnorm : cnorm;
    const int       lg  = isE ? 3 : 6;
    const int       kts = isE ? 8 : 64;
    const size_t R0 = (size_t)(isE ? bid : bid - NROW / 32) * 32;

    const int t = threadIdx.x;

    #pragma unroll
    for (int p = 0; p < 16; ++p) {
        int idx = p * 1024 + t * 4;
        float4 v = *(const float4*)(src + R0 * Cc + idx);
        u16x4 o;
        o[0] = bf16_rne(v.x); o[1] = bf16_rne(v.y);
        o[2] = bf16_rne(v.z); o[3] = bf16_rne(v.w);
        *(u16x4*)&buf[idx] = o;
    }
    __syncthreads();

    const int w = t >> 6, g = (t >> 4) & 3, q = t & 15, l = t & 63;
    const int rb = (int)(R0 >> 4);
    const int rowblk_base = rb + (rb >> lg) * (15 << lg);
    float fns = 0.f;
    #pragma unroll
    for (int p = 0; p < 8; ++p) {
        int cg  = p * 4 + w;              // tile-local group 0..31
        int kt  = cg >> 1, nrt = cg & 1;
        int row = nrt * 16 + q;
        u16x8 ch = *(const u16x8*)&buf[row * 512 + kt * 32 + g * 8];
        #pragma unroll
        for (int i = 0; i < 8; ++i) {
            float x = __uint_as_float((unsigned int)(unsigned short)ch[i] << 16);
            fns = fmaf(x, x, fns);
        }
        size_t tile = (size_t)rowblk_base + (size_t)kt * kts + nrt;
        *(u16x8*)(dst + tile * 512 + l * 8) = ch;
    }
    snorm[((w & 1) * 16 + q) * 8 + (w >> 1) * 4 + g] = fns;
    __syncthreads();
    if (t < 32) {
        float s = 0.f;
        #pragma unroll
        for (int j = 0; j < 8; ++j) s += snorm[t * 8 + j];
        nrm[R0 + t] = s;
    }
}

// ---------------------------------------------------------------------------
// Main (R12 proven structure, restored verbatim): split-pipe 128x128 MFMA
// tile, TWO k-steps per barrier (32 MFMA/wave between barriers). A fragments
// direct global->VGPR prefetched 2 k-steps ahead (compiler-counted reg
// waits). B double-buffered 2x16KB via gload_lds (4 DMA/thread per iter);
// counted vmcnt(8) per step drains next iter's B, keeps the 8 A loads in
// flight (never 0 until tail). Fragment-ordered reads: contiguous 1KB/wave
// => conflict-free, no swizzle. Swapped-operand MFMA (cents lane-local in
// C) + packed-u32 top-3. NOTE: register footprint is ~68 VGPR + 64 AGPR;
// __launch_bounds__(256,3) is the max occupancy this admits -- capping
// higher (R14: (256,5)) forces a catastrophic scratch spill.
// Grid: 1600 blocks (200 padded mblocks x 8 pblocks), 256 thr = 4 waves 2x2.
// acc[mc][nr]: cent = p0+wn*64+mc*16+g*4+reg ; row = row0+wm*64+nr*16+q
// ---------------------------------------------------------------------------
__global__ __launch_bounds__(256, 3) void mfma_topk_kernel(
        const unsigned short* __restrict__ EbT, const unsigned short* __restrict__ CbT,
        const float* __restrict__ cnorm, float* __restrict__ wsTop) {
    const int xcd = blockIdx.x & 7;
    const int t8  = blockIdx.x >> 3;          // 0..199
    const int mblock = ((t8 >> 3) << 3) | xcd;
    const int pblock = t8 & 7;
    if (mblock >= NMB) return;                // uniform early-exit

    __shared__ unsigned short Blds[2][8192];  // 2 x 16 KB (2 k-panels each)
    __shared__ float tops[2][BM][3];          // 3 KB

    const int tid  = threadIdx.x;
    const int lane = tid & 63;
    const int w    = tid >> 6;
    const int wm   = w >> 1;       // 0..1 row half
    const int wn   = w & 1;        // 0..1 cent half
    const int g    = lane >> 4;    // 0..3
    const int q    = lane & 15;    // 0..15
    const int row0 = mblock * BM;
    const int p0   = pblock * BNP;

    f32x4 acc[4][4];               // [mc][nr]
    #pragma unroll
    for (int mc = 0; mc < 4; ++mc)
        #pragma unroll
        for (int nr = 0; nr < 4; ++nr) acc[mc][nr] = (f32x4){0.f, 0.f, 0.f, 0.f};

    // A fragment base (u16): tile=512 u16, tiles [mblock][kt 16][nrt 8]
    const unsigned short* Ab = EbT + ((size_t)mblock * 128 + wm * 4) * 512 + lane * 8;
    // B: tiles [kt 16][ptile 64]; this block's 8 tiles per kt are contiguous
    const unsigned short* Bg = CbT + (size_t)pblock * 8 * 512;

    // stage TWO k-panels (kt = 2i, 2i+1) into buffer buf: 4 DMA instrs/thread
    auto STAGE_B2 = [&](int buf, int i) {
        #pragma unroll
        for (int ks = 0; ks < 2; ++ks) {
            const unsigned short* src = Bg + (size_t)(2 * i + ks) * 32768;
            #pragma unroll
            for (int it = 0; it < 2; ++it) {
                int c = tid + it * 256;
                GLOAD_LDS16(src + c * 8, (char*)Blds[buf] + ks * 8192 + c * 16);
            }
        }
    };

    bf16x8 af[2][2][4];            // [buf][ks][nr] = 64 VGPR
    STAGE_B2(0, 0);                // B iter0 (kt 0,1): 4 DMA
    #pragma unroll
    for (int ks = 0; ks < 2; ++ks)
        #pragma unroll
        for (int nr = 0; nr < 4; ++nr)
            af[0][ks][nr] = *(const bf16x8*)(Ab + (size_t)ks * 4096 + nr * 512);
    // in flight: B0(4 oldest) + A0(8) -> drain B0, keep A0
    asm volatile("s_waitcnt vmcnt(8)" ::: "memory");
    __builtin_amdgcn_s_barrier();

    #pragma unroll
    for (int i = 0; i < 8; ++i) {
        const int cur = i & 1, nxt = cur ^ 1;
        if (i < 7) {
            STAGE_B2(nxt, i + 1);                      // 4 DMA
            #pragma unroll
            for (int ks = 0; ks < 2; ++ks)
                #pragma unroll
                for (int nr = 0; nr < 4; ++nr)
                    af[nxt][ks][nr] = *(const bf16x8*)(
                        Ab + (size_t)(2 * i + 2 + ks) * 4096 + nr * 512);
        }

        #pragma unroll
        for (int ks = 0; ks < 2; ++ks) {
            const char* Bsk = (const char*)Blds[cur] + ks * 8192;
            bf16x8 bc[4];
            #pragma unroll
            for (int mc = 0; mc < 4; ++mc)
                bc[mc] = *(const bf16x8*)(Bsk + (wn * 4 + mc) * 1024 + lane * 16);
            __builtin_amdgcn_s_setprio(1);
            #pragma unroll
            for (int mc = 0; mc < 4; ++mc)
                #pragma unroll
                for (int nr = 0; nr < 4; ++nr)
                    acc[mc][nr] = __builtin_amdgcn_mfma_f32_16x16x32_bf16(
                        bc[mc], af[cur][ks][nr], acc[mc][nr], 0, 0, 0);
            __builtin_amdgcn_s_setprio(0);
        }

        // drain next iter's B(4); keep next iter's A(8) in flight
        if (i < 7) asm volatile("s_waitcnt vmcnt(8)" ::: "memory");
        else       asm volatile("s_waitcnt vmcnt(0)" ::: "memory");
        __builtin_amdgcn_s_barrier();
    }

    // ---- epilogue: cents lane-local; top-3 per row over 64 cents/wave ----
    float cnb[4][4];
    #pragma unroll
    for (int mc = 0; mc < 4; ++mc)
        #pragma unroll
        for (int reg = 0; reg < 4; ++reg)
            cnb[mc][reg] = cnorm[p0 + wn * 64 + mc * 16 + g * 4 + reg] + BIAS;

    #pragma unroll
    for (int nr = 0; nr < 4; ++nr) {
        unsigned int u0 = 0xFFFFFFFFu, u1 = 0xFFFFFFFFu, u2 = 0xFFFFFFFFu;
        #pragma unroll
        for (int mc = 0; mc < 4; ++mc)
            #pragma unroll
            for (int reg = 0; reg < 4; ++reg) {
                float v = fmaf(-2.f, acc[mc][nr][reg], cnb[mc][reg]);  // > 0
                unsigned int cl = (unsigned int)(wn * 64 + mc * 16 + g * 4 + reg);
                unsigned int u = (__float_as_uint(v) & 0xFFFFFF00u) | cl;
                TOP3_INS_U32(u0, u1, u2, u);
            }
        #pragma unroll
        for (int mask = 16; mask <= 32; mask <<= 1) {
            unsigned int o0 = (unsigned int)__shfl_xor((int)u0, mask);
            unsigned int o1 = (unsigned int)__shfl_xor((int)u1, mask);
            unsigned int o2 = (unsigned int)__shfl_xor((int)u2, mask);
            TOP3_INS_U32(u0, u1, u2, o0);
            TOP3_INS_U32(u0, u1, u2, o1);
            TOP3_INS_U32(u0, u1, u2, o2);
        }
        if (g == 0) {
            int rl = wm * 64 + nr * 16 + q;
            tops[wn][rl][0] = __uint_as_float(u0 & 0xFFFFFF00u) - BIAS;
            tops[wn][rl][1] = __uint_as_float(u1 & 0xFFFFFF00u) - BIAS;
            tops[wn][rl][2] = __uint_as_float(u2 & 0xFFFFFF00u) - BIAS;
        }
    }
    __syncthreads();

    if (tid < BM) {
        float a0v = tops[0][tid][0], a1v = tops[0][tid][1], a2v = tops[0][tid][2];
        TOP3_INSERT(a0v, a1v, a2v, tops[1][tid][0]);
        TOP3_INSERT(a0v, a1v, a2v, tops[1][tid][1]);
        TOP3_INSERT(a0v, a1v, a2v, tops[1][tid][2]);
        float* dst = wsTop + (size_t)(row0 + tid) * 24 + pblock * 3;
        dst[0] = a0v; dst[1] = a1v; dst[2] = a2v;
    }
}

// ---------------------------------------------------------------------------
// Final merge: fold 8 pblocks' top3, add row norm, sqrt + softmin, store.
// ---------------------------------------------------------------------------
__global__ __launch_bounds__(256) void merge_kernel(
        const float* __restrict__ wsTop, const float* __restrict__ fnorm,
        float* __restrict__ out) {
    int r = blockIdx.x * 256 + threadIdx.x;      // 25088 = 98*256 exact
    const float* p = wsTop + (size_t)r * 24;
    float t0 = p[0], t1 = p[1], t2 = p[2];
    #pragma unroll
    for (int pb = 1; pb < 8; ++pb) {
        TOP3_INSERT(t0, t1, t2, p[pb * 3 + 0]);
        TOP3_INSERT(t0, t1, t2, p[pb * 3 + 1]);
        TOP3_INSERT(t0, t1, t2, p[pb * 3 + 2]);
    }
    float fn = fnorm[r];
    float d0 = sqrtf(fmaxf(fn + t0, 0.f));
    float d1 = sqrtf(fmaxf(fn + t1, 0.f));
    float d2 = sqrtf(fmaxf(fn + t2, 0.f));
    float w0 = 1.f / (1.f + __expf(d0 - d1) + __expf(d0 - d2));
    out[r] = w0 * d0;
}

extern "C" void kernel_launch(void* const* d_in, const int* in_sizes, int n_in,
                              void* d_out, int out_size, void* d_ws, size_t ws_size,
                              hipStream_t stream) {
    (void)in_sizes; (void)n_in; (void)out_size; (void)ws_size;
    const float* embeds    = (const float*)d_in[0];   // [8,3136,512] fp32
    const float* centroids = (const float*)d_in[1];   // [1024,512]  fp32
    float* out = (float*)d_out;

    // ws layout (bytes):
    //   cnorm  @ 0         (4 KB)
    //   fnorm  @ 4096      (100,352 B)
    //   wsTop  @ 104448    (25088*8*3*4 = 2,408,448 B)  [row][pblock][3]
    //   EbT    @ 2512896   (25,690,112 B bf16, fragment-tiled)
    //   CbT    @ 28203008  (1,048,576 B bf16, fragment-tiled)  total ~27.9 MB
    char* ws = (char*)d_ws;
    float*          cnorm = (float*)(ws);
    float*          fnorm = (float*)(ws + 4096);
    float*          wsTop = (float*)(ws + 104448);
    unsigned short* EbT   = (unsigned short*)(ws + 2512896);
    unsigned short* CbT   = (unsigned short*)(ws + 28203008);

    tconv_fused_kernel<<<NROW / 32 + Pp / 32, 256, 0, stream>>>(
        embeds, centroids, EbT, CbT, fnorm, cnorm);
    mfma_topk_kernel<<<NMB_PAD * 8, 256, 0, stream>>>(EbT, CbT, cnorm, wsTop);
    merge_kernel<<<NROW / 256, 256, 0, stream>>>(wsTop, fnorm, out);
}